// Round 7
// baseline (142.464 us; speedup 1.0000x reference)
//
#include <hip/hip_runtime.h>
#include <math.h>

// BoundaryMaxPooling: out[b,c,t] = max(feature[b,c, lo[t]:hi[t]])
// Queries from batch-0 segments: start half (c<512) / end half (c>=512).
// B=8, C2=1024, T=2048, float32.
//
// Per-row structure in LDS (float indices):
//   W1  [0,2048)     : the row itself (sliding window 1)
//   W2  [2064,+2048) : W2[i] = max(row[i..i+1])
//   W8  [4128,+2048) : W8[i] = max(row[i..i+7])
//   MT  [6192,+1536) : level k in [0,5]: MT_k[j] = max over chunks j..j+2^k-1
//                      (chunk j = row[8j..8j+7]; level 0 = chunk maxes)
//   SENT 7728        : -inf sentinel
// Every query = max of exactly 4 LDS values at indices precomputed in prep.
// R7: query descriptors prefetched to VGPRs at entry (hidden under build);
//     each thread produces 8 consecutive outputs -> 2x global_store_dwordx4.

#define T_DIM   2048
#define C2_DIM  1024
#define B_DIM   8
#define NT      256

#define W1B   0
#define W2B   2064
#define W8B   4128
#define MTB   6192
#define SENTI 7728
#define LDS_FLOATS 7729

__device__ __forceinline__ int4 make_q(int lo, int hi1) {
    // inclusive range [lo, hi1], 0 <= lo <= hi1 <= 2047, len <= 257
    int len = hi1 - lo + 1;
    if (len <= 2) {
        return make_int4(W1B + lo, W1B + hi1, W1B + lo, W1B + hi1);
    } else if (len == 3) {
        return make_int4(W1B + lo, W1B + lo + 1, W1B + hi1, SENTI);
    } else if (len <= 8) {
        // four width-2 windows cover up to 8 elements, all inside [lo,hi1]
        return make_int4(W2B + lo, W2B + lo + 2, W2B + hi1 - 3, W2B + hi1 - 1);
    } else {
        int d0 = lo >> 3, d1 = hi1 >> 3;
        int m = d1 - d0 - 1;          // interior full chunks
        int i3 = SENTI, i4 = SENTI;
        if (m > 0) {
            int kc = 31 - __clz(m);   // floor(log2 m), m <= 32 -> kc <= 5
            if (kc > 5) kc = 5;
            i3 = MTB + kc * 256 + d0 + 1;
            i4 = MTB + kc * 256 + d1 - (1 << kc);
        }
        return make_int4(W8B + lo, W8B + hi1 - 7, i3, i4);
    }
}

__global__ void prep_kernel(const float* __restrict__ seg, int4* __restrict__ qidx) {
    int t = blockIdx.x * blockDim.x + threadIdx.x;
    if (t >= T_DIM) return;
    float4 s = reinterpret_cast<const float4*>(seg)[t];   // batch-0 segments
    const float cm = (float)(T_DIM - 1);
    float a = fminf(fmaxf(s.x, 0.f), cm);
    float b = fminf(fmaxf(s.y, 0.f), cm);
    float c = fminf(fmaxf(s.z, 0.f), cm);
    float d = fminf(fmaxf(s.w, 0.f), cm);
    int lo_s = (int)floorf(a);
    int hi_s = max((int)ceilf(b), lo_s + 1) - 1;
    int lo_e = (int)floorf(c);
    int hi_e = max((int)ceilf(d), lo_e + 1) - 1;
    qidx[t]         = make_q(lo_s, hi_s);
    qidx[T_DIM + t] = make_q(lo_e, hi_e);
}

__device__ __forceinline__ float max4f(float a, float b, float c, float d) {
    return fmaxf(fmaxf(a, b), fmaxf(c, d));
}

__global__ __launch_bounds__(NT) void bmp_kernel(
    const float* __restrict__ feature, const int4* __restrict__ qidx,
    float* __restrict__ out)
{
    __shared__ __align__(16) float L[LDS_FLOATS];
    const int tid = threadIdx.x;
    const int bc  = blockIdx.x;                 // b*1024 + c
    const int c   = bc & (C2_DIM - 1);
    const size_t rowoff = (size_t)bc * T_DIM;
    const float4* src = reinterpret_cast<const float4*>(feature + rowoff);

    // issue row loads (own 16 floats; last thread clamps — its upper 8 only
    // feed never-queried structure entries)
    int f4i = 2 * tid;
    float4 A  = src[f4i];
    float4 Bv = src[f4i + 1];
    float4 Cv = src[min(f4i + 2, T_DIM / 4 - 1)];
    float4 Dv = src[min(f4i + 3, T_DIM / 4 - 1)];

    // prefetch this thread's 8 query descriptors (independent of the build —
    // latency hides under the LDS staging + window construction)
    const int4* qbase = qidx + ((c >= C2_DIM / 2) ? T_DIM : 0) + tid * 8;
    int4 qv[8];
#pragma unroll
    for (int j = 0; j < 8; ++j) qv[j] = qbase[j];

    float r[16] = {A.x, A.y, A.z, A.w, Bv.x, Bv.y, Bv.z, Bv.w,
                   Cv.x, Cv.y, Cv.z, Cv.w, Dv.x, Dv.y, Dv.z, Dv.w};

    // stage row (own 8 floats, contiguous -> b128 writes)
    *reinterpret_cast<float4*>(&L[W1B + 8 * tid])     = A;
    *reinterpret_cast<float4*>(&L[W1B + 8 * tid + 4]) = Bv;

    // sliding windows entirely in registers
    float w2[14];
#pragma unroll
    for (int k = 0; k < 14; ++k) w2[k] = fmaxf(r[k], r[k + 1]);
    float w4[12];
#pragma unroll
    for (int k = 0; k < 12; ++k) w4[k] = fmaxf(w2[k], w2[k + 2]);
    float w8v[8];
#pragma unroll
    for (int k = 0; k < 8; ++k) w8v[k] = fmaxf(w4[k], w4[k + 4]);

    *reinterpret_cast<float4*>(&L[W2B + 8 * tid])     = make_float4(w2[0], w2[1], w2[2], w2[3]);
    *reinterpret_cast<float4*>(&L[W2B + 8 * tid + 4]) = make_float4(w2[4], w2[5], w2[6], w2[7]);
    *reinterpret_cast<float4*>(&L[W8B + 8 * tid])     = make_float4(w8v[0], w8v[1], w8v[2], w8v[3]);
    *reinterpret_cast<float4*>(&L[W8B + 8 * tid + 4]) = make_float4(w8v[4], w8v[5], w8v[6], w8v[7]);
    L[MTB + tid] = w8v[0];                      // chunk max (level 0)
    if (tid == 0) L[SENTI] = -INFINITY;
    __syncthreads();

    // sparse-table levels 1..5 over chunk maxes: thread t computes windows
    // starting at chunk t from 32 conflict-free reads (lane j hits bank j%32)
    float v[32];
#pragma unroll
    for (int k = 0; k < 32; ++k) v[k] = L[MTB + min(tid + k, 255)];
    float p2  = fmaxf(v[0], v[1]);
    float p4  = fmaxf(p2, fmaxf(v[2], v[3]));
    float t47 = max4f(v[4], v[5], v[6], v[7]);
    float p8  = fmaxf(p4, t47);
    float t8  = fmaxf(max4f(v[8], v[9], v[10], v[11]),
                      max4f(v[12], v[13], v[14], v[15]));
    float p16 = fmaxf(p8, t8);
    float t16 = fmaxf(fmaxf(max4f(v[16], v[17], v[18], v[19]),
                            max4f(v[20], v[21], v[22], v[23])),
                      fmaxf(max4f(v[24], v[25], v[26], v[27]),
                            max4f(v[28], v[29], v[30], v[31])));
    float p32 = fmaxf(p16, t16);
    L[MTB + 256  + tid] = p2;
    L[MTB + 512  + tid] = p4;
    L[MTB + 768  + tid] = p8;
    L[MTB + 1024 + tid] = p16;
    L[MTB + 1280 + tid] = p32;
    __syncthreads();

    // branchless queries: 4 LDS reads + 3 fmax each; 8 consecutive outputs
    // per thread -> two dwordx4 stores
    float res[8];
#pragma unroll
    for (int j = 0; j < 8; ++j) {
        int4 ix = qv[j];
        res[j] = max4f(L[ix.x], L[ix.y], L[ix.z], L[ix.w]);
    }
    float4* dst4 = reinterpret_cast<float4*>(out + rowoff + tid * 8);
    dst4[0] = make_float4(res[0], res[1], res[2], res[3]);
    dst4[1] = make_float4(res[4], res[5], res[6], res[7]);
}

extern "C" void kernel_launch(void* const* d_in, const int* in_sizes, int n_in,
                              void* d_out, int out_size, void* d_ws, size_t ws_size,
                              hipStream_t stream) {
    const float* feature  = (const float*)d_in[0];
    const float* segments = (const float*)d_in[1];
    float* out = (float*)d_out;
    int4* qidx = (int4*)d_ws;   // [2*T_DIM] int4 query descriptors

    prep_kernel<<<T_DIM / NT, NT, 0, stream>>>(segments, qidx);
    bmp_kernel<<<B_DIM * C2_DIM, NT, 0, stream>>>(feature, qidx, out);
}

// Round 11
// 117.715 us; speedup vs baseline: 1.2102x; 1.2102x over previous
//
#include <hip/hip_runtime.h>
#include <math.h>

// BoundaryMaxPooling: out[b,c,t] = max(feature[b,c, lo[t]:hi[t]])
// Queries from batch-0 segments: start half (c<512) / end half (c>=512).
// B=8, C2=1024, T=2048, float32.
//
// Per-row structure in LDS (float indices), all LINEAR (R6 verified layout;
// build writes are only 2-way bank-aliased, which is free on CDNA4 [m136]):
//   W1  [0,2048)     : the row itself (sliding window 1)
//   W2  [2064,+2048) : W2[i] = max(row[i..i+1])
//   W8  [4128,+2048) : W8[i] = max(row[i..i+7])
//   MT  [6192,+1536) : level k in [0,5]: MT_k[j] = max over chunks j..j+2^k-1
//   SENT 7728        : -inf sentinel
// Every query = max of exactly 4 LDS values at indices precomputed in prep.
// R9 = R6 + coalesced descriptor prefetch issued before the build (latency
// hidden under LDS staging) + coalesced nontemporal output stores.

#define T_DIM   2048
#define C2_DIM  1024
#define B_DIM   8
#define NT      256

#define W1B   0
#define W2B   2064
#define W8B   4128
#define MTB   6192
#define SENTI 7728
#define LDS_FLOATS 7729

__device__ __forceinline__ int4 make_q(int lo, int hi1) {
    // inclusive range [lo, hi1], 0 <= lo <= hi1 <= 2047, len <= 257
    int len = hi1 - lo + 1;
    if (len <= 2) {
        return make_int4(W1B + lo, W1B + hi1, W1B + lo, W1B + hi1);
    } else if (len == 3) {
        return make_int4(W1B + lo, W1B + lo + 1, W1B + hi1, SENTI);
    } else if (len <= 8) {
        // four width-2 windows cover up to 8 elements, all inside [lo,hi1]
        return make_int4(W2B + lo, W2B + lo + 2, W2B + hi1 - 3, W2B + hi1 - 1);
    } else {
        int d0 = lo >> 3, d1 = hi1 >> 3;
        int m = d1 - d0 - 1;          // interior full chunks
        int i3 = SENTI, i4 = SENTI;
        if (m > 0) {
            int kc = 31 - __clz(m);   // floor(log2 m), m <= 32 -> kc <= 5
            if (kc > 5) kc = 5;
            i3 = MTB + kc * 256 + d0 + 1;
            i4 = MTB + kc * 256 + d1 - (1 << kc);
        }
        return make_int4(W8B + lo, W8B + hi1 - 7, i3, i4);
    }
}

__global__ void prep_kernel(const float* __restrict__ seg, int4* __restrict__ qidx) {
    int t = blockIdx.x * blockDim.x + threadIdx.x;
    if (t >= T_DIM) return;
    float4 s = reinterpret_cast<const float4*>(seg)[t];   // batch-0 segments
    const float cm = (float)(T_DIM - 1);
    float a = fminf(fmaxf(s.x, 0.f), cm);
    float b = fminf(fmaxf(s.y, 0.f), cm);
    float c = fminf(fmaxf(s.z, 0.f), cm);
    float d = fminf(fmaxf(s.w, 0.f), cm);
    int lo_s = (int)floorf(a);
    int hi_s = max((int)ceilf(b), lo_s + 1) - 1;
    int lo_e = (int)floorf(c);
    int hi_e = max((int)ceilf(d), lo_e + 1) - 1;
    qidx[t]         = make_q(lo_s, hi_s);
    qidx[T_DIM + t] = make_q(lo_e, hi_e);
}

__device__ __forceinline__ float max4f(float a, float b, float c, float d) {
    return fmaxf(fmaxf(a, b), fmaxf(c, d));
}

__global__ __launch_bounds__(NT) void bmp_kernel(
    const float* __restrict__ feature, const int4* __restrict__ qidx,
    float* __restrict__ out)
{
    __shared__ __align__(16) float L[LDS_FLOATS];
    const int tid = threadIdx.x;
    const int bc  = blockIdx.x;                 // b*1024 + c
    const int c   = bc & (C2_DIM - 1);
    const size_t rowoff = (size_t)bc * T_DIM;
    const float4* src = reinterpret_cast<const float4*>(feature + rowoff);

    // issue row loads (own 16 floats; last thread clamps — its upper 8 only
    // feed never-queried structure entries)
    int f4i = 2 * tid;
    float4 A  = src[f4i];
    float4 Bv = src[f4i + 1];
    float4 Cv = src[min(f4i + 2, T_DIM / 4 - 1)];
    float4 Dv = src[min(f4i + 3, T_DIM / 4 - 1)];

    // prefetch query descriptors in the COALESCED interleaved layout
    // (16B/lane per instruction); latency hides under the LDS build
    const int4* q = qidx + ((c >= C2_DIM / 2) ? T_DIM : 0);
    int4 qv[8];
#pragma unroll
    for (int j = 0; j < 8; ++j) qv[j] = q[tid + j * NT];

    float r[16] = {A.x, A.y, A.z, A.w, Bv.x, Bv.y, Bv.z, Bv.w,
                   Cv.x, Cv.y, Cv.z, Cv.w, Dv.x, Dv.y, Dv.z, Dv.w};

    // stage row (own 8 floats, contiguous -> b128 writes)
    *reinterpret_cast<float4*>(&L[W1B + 8 * tid])     = A;
    *reinterpret_cast<float4*>(&L[W1B + 8 * tid + 4]) = Bv;

    // sliding windows entirely in registers
    float w2[14];
#pragma unroll
    for (int k = 0; k < 14; ++k) w2[k] = fmaxf(r[k], r[k + 1]);
    float w4[12];
#pragma unroll
    for (int k = 0; k < 12; ++k) w4[k] = fmaxf(w2[k], w2[k + 2]);
    float w8v[8];
#pragma unroll
    for (int k = 0; k < 8; ++k) w8v[k] = fmaxf(w4[k], w4[k + 4]);

    *reinterpret_cast<float4*>(&L[W2B + 8 * tid])     = make_float4(w2[0], w2[1], w2[2], w2[3]);
    *reinterpret_cast<float4*>(&L[W2B + 8 * tid + 4]) = make_float4(w2[4], w2[5], w2[6], w2[7]);
    *reinterpret_cast<float4*>(&L[W8B + 8 * tid])     = make_float4(w8v[0], w8v[1], w8v[2], w8v[3]);
    *reinterpret_cast<float4*>(&L[W8B + 8 * tid + 4]) = make_float4(w8v[4], w8v[5], w8v[6], w8v[7]);
    L[MTB + tid] = w8v[0];                      // chunk max (level 0)
    if (tid == 0) L[SENTI] = -INFINITY;
    __syncthreads();

    // sparse-table levels 1..5 over chunk maxes: thread t computes windows
    // starting at chunk t from 32 conflict-free reads
    float v[32];
#pragma unroll
    for (int k = 0; k < 32; ++k) v[k] = L[MTB + min(tid + k, 255)];
    float p2  = fmaxf(v[0], v[1]);
    float p4  = fmaxf(p2, fmaxf(v[2], v[3]));
    float t47 = max4f(v[4], v[5], v[6], v[7]);
    float p8  = fmaxf(p4, t47);
    float t8  = fmaxf(max4f(v[8], v[9], v[10], v[11]),
                      max4f(v[12], v[13], v[14], v[15]));
    float p16 = fmaxf(p8, t8);
    float t16 = fmaxf(fmaxf(max4f(v[16], v[17], v[18], v[19]),
                            max4f(v[20], v[21], v[22], v[23])),
                      fmaxf(max4f(v[24], v[25], v[26], v[27]),
                            max4f(v[28], v[29], v[30], v[31])));
    float p32 = fmaxf(p16, t16);
    L[MTB + 256  + tid] = p2;
    L[MTB + 512  + tid] = p4;
    L[MTB + 768  + tid] = p8;
    L[MTB + 1024 + tid] = p16;
    L[MTB + 1280 + tid] = p32;
    __syncthreads();

    // branchless queries: 4 LDS reads + 3 fmax each; coalesced nt stores
    float* dst = out + rowoff;
#pragma unroll
    for (int j = 0; j < 8; ++j) {
        int4 ix = qv[j];
        float res = max4f(L[ix.x], L[ix.y], L[ix.z], L[ix.w]);
        __builtin_nontemporal_store(res, dst + tid + j * NT);
    }
}

extern "C" void kernel_launch(void* const* d_in, const int* in_sizes, int n_in,
                              void* d_out, int out_size, void* d_ws, size_t ws_size,
                              hipStream_t stream) {
    const float* feature  = (const float*)d_in[0];
    const float* segments = (const float*)d_in[1];
    float* out = (float*)d_out;
    int4* qidx = (int4*)d_ws;   // [2*T_DIM] int4 query descriptors

    prep_kernel<<<T_DIM / NT, NT, 0, stream>>>(segments, qidx);
    bmp_kernel<<<B_DIM * C2_DIM, NT, 0, stream>>>(feature, qidx, out);
}